// Round 16
// baseline (376.049 us; speedup 1.0000x reference)
//
#include <hip/hip_runtime.h>
#include <hip/hip_bf16.h>
#include <math.h>

#define BB   8
#define LL   2048
#define DD   1024
#define HH   16
#define DKK  64
#define TOPK 7

typedef unsigned short u16;
typedef short short8 __attribute__((ext_vector_type(8)));
typedef short s4v    __attribute__((ext_vector_type(4)));
typedef float f32x4  __attribute__((ext_vector_type(4)));
typedef int   int4v  __attribute__((ext_vector_type(4)));
typedef unsigned int uint2v __attribute__((ext_vector_type(2)));

// ---- workspace layout (BYTE offsets), high-water = 209,715,200 B ----
#define QXH_B   0ull
#define QXL_B   16777216ull
#define KXH_B   33554432ull
#define KXL_B   50331648ull
#define VXH_B   67108864ull
#define QWH_B   100663296ull
#define QWL_B   101711872ull
#define KWH_B   102760448ull
#define KWL_B   103809024ull
#define VWH_B   104857600ull
#define OWH_B   106954752ull
#define QTB_B   109051904ull
#define KTB_B   142606336ull
#define VBF_B   176160768ull
#define PART_B  0ull
#define PART_STRIDE 2064
#define TOPW_B  16777216ull
#define TOPI_B  16780800ull

#define SX_INV  5461.3333f
#define SW_INV  174762.67f
#define CS1     6.8664551e-5f
#define CS2     2.6822090e-7f

// ---------------------------------------------------------------------------
// helpers
// ---------------------------------------------------------------------------
__device__ __forceinline__ u16 f2bf(float f) {
    unsigned u = __float_as_uint(f);
    unsigned r = u + 0x7FFFu + ((u >> 16) & 1u);
    return (u16)(r >> 16);
}
__device__ __forceinline__ float bf2f(u16 h) {
    return __uint_as_float((unsigned)h << 16);
}

// 8 elems/thread: 2x float4 load, hi/lo each packed into one 8B store
__device__ __forceinline__ void split8_i8(const float* __restrict__ x,
                                          char* __restrict__ hi,
                                          char* __restrict__ lo,
                                          float inv_s, size_t i) {
    const float4* xp = (const float4*)(x + i * 8);
    float4 t0 = xp[0], t1 = xp[1];
    float f[8] = {t0.x, t0.y, t0.z, t0.w, t1.x, t1.y, t1.z, t1.w};
    uint2v hp = (uint2v){0u, 0u}, lp = (uint2v){0u, 0u};
    #pragma unroll
    for (int j = 0; j < 8; ++j) {
        int q = __float2int_rn(f[j] * inv_s);
        q = min(max(q, -32639), 32639);
        int xl = ((q + 128) & 255) - 128;
        int xh = (q - xl) >> 8;
        hp[j >> 2] |= ((unsigned)(xh & 255)) << (8 * (j & 3));
        lp[j >> 2] |= ((unsigned)(xl & 255)) << (8 * (j & 3));
    }
    *(uint2v*)(hi + i * 8) = hp;
    *(uint2v*)(lo + i * 8) = lp;
}

// 8 elems/thread: 2x float4 load -> one short8 bf16 store (16B)
__device__ __forceinline__ void cvt8_bf(const float* __restrict__ x,
                                        u16* __restrict__ o, size_t i) {
    const float4* xp = (const float4*)(x + i * 8);
    float4 t0 = xp[0], t1 = xp[1];
    float f[8] = {t0.x, t0.y, t0.z, t0.w, t1.x, t1.y, t1.z, t1.w};
    short8 h;
    #pragma unroll
    for (int j = 0; j < 8; ++j) h[j] = (short)f2bf(f[j]);
    *(short8*)(o + i * 8) = h;
}

// ---------------------------------------------------------------------------
// ALL conversions, one launch, 8 elems/thread.
// ---------------------------------------------------------------------------
__global__ __launch_bounds__(256) void k_conv_all(
    const float* __restrict__ q, const float* __restrict__ k,
    const float* __restrict__ v,
    const float* __restrict__ Wq, const float* __restrict__ Wk,
    const float* __restrict__ Wv, const float* __restrict__ Wo,
    char* __restrict__ qh, char* __restrict__ ql,
    char* __restrict__ kh, char* __restrict__ kl, u16* __restrict__ vx,
    char* __restrict__ qwh, char* __restrict__ qwl,
    char* __restrict__ kwh, char* __restrict__ kwl,
    u16* __restrict__ vwh, u16* __restrict__ owh)
{
    const int b = blockIdx.x;
    const int t = threadIdx.x;
    if (b < 8192) {
        split8_i8(q, qh, ql, SX_INV, (size_t)b * 256 + t);
    } else if (b < 16384) {
        split8_i8(k, kh, kl, SX_INV, (size_t)(b - 8192) * 256 + t);
    } else if (b < 24576) {
        cvt8_bf(v, vx, (size_t)(b - 16384) * 256 + t);
    } else if (b < 25088) {
        split8_i8(Wq, qwh, qwl, SW_INV, (size_t)(b - 24576) * 256 + t);
    } else if (b < 25600) {
        split8_i8(Wk, kwh, kwl, SW_INV, (size_t)(b - 25088) * 256 + t);
    } else if (b < 26112) {
        cvt8_bf(Wv, vwh, (size_t)(b - 25600) * 256 + t);
    } else {
        cvt8_bf(Wo, owh, (size_t)(b - 26112) * 256 + t);
    }
}

// ---------------------------------------------------------------------------
// async global->LDS (16B, wave-uniform LDS base + lane*16)
// ---------------------------------------------------------------------------
__device__ __forceinline__ void async16(u16* l, const u16* g) {
    __builtin_amdgcn_global_load_lds(
        (const __attribute__((address_space(1))) void*)g,
        (__attribute__((address_space(3))) void*)l, 16, 0, 0);
}
__device__ __forceinline__ void async16b(char* l, const char* g) {
    __builtin_amdgcn_global_load_lds(
        (const __attribute__((address_space(1))) void*)g,
        (__attribute__((address_space(3))) void*)l, 16, 0, 0);
}

// ---------------------------------------------------------------------------
// MERGED 256x128 phase-pipelined i8-split GEMM, CONFLICT-FREE LDS layout:
// tile stored as [rowblk16][slot(4)][row16] -> addr = (row>>4)*1024 +
// slot*256 + (row&15)*16. Fragment read by 64 lanes = 1024B contiguous
// (zero bank conflicts). Staging: wave wid stages rowblk wid (16 rows x 64B),
// lane l -> row rowbase+wid*16+(l&15), k-chunk (l>>4). Math identical.
// ---------------------------------------------------------------------------
__global__ __launch_bounds__(512, 2) void gemm_i8_qk(
    const char* __restrict__ qAh, const char* __restrict__ qAl,
    const char* __restrict__ qBh, const char* __restrict__ qBl,
    const float* __restrict__ qbias, u16* __restrict__ qout,
    const char* __restrict__ kAh, const char* __restrict__ kAl,
    const char* __restrict__ kBh, const char* __restrict__ kBl,
    const float* __restrict__ kbias, u16* __restrict__ kout)
{
    extern __shared__ char ldsc[];
    char* lAh = ldsc;
    char* lAl = ldsc + 32768;
    char* lBh = ldsc + 65536;
    char* lBl = ldsc + 81920;
    const int t = threadIdx.x;
    const int wid = t >> 6, lane = t & 63;
    const int wr = wid >> 1, wc = wid & 1;
    const int r15 = lane & 15, kg = lane >> 4, r4 = kg * 4;
    const int lin = blockIdx.y * gridDim.x + blockIdx.x;   // [0,1024)
    const int set = lin >> 9;                              // 0=Q, 1=K
    const int l2  = lin & 511;
    const int swz = (l2 & 7) * 64 + (l2 >> 3);             // bijective per set
    const int n0 = (swz & 7) * 128, m0 = (swz >> 3) * 256;
    const char* Ah = set ? kAh : qAh;
    const char* Al = set ? kAl : qAl;
    const char* Bh = set ? kBh : qBh;
    const char* Bl = set ? kBl : qBl;
    const float* bias = set ? kbias : qbias;
    u16* outb = set ? kout : qout;
    const int fro = kg * 256 + r15 * 16;   // fragment-read offset within rowblk

    // stage one 8KB unit: wave wid stages rowblk (rowbase/16 + wid)
    #define STGU(ls, bufb, bufsz, rowbase, src, base0, kt)                      \
    {                                                                           \
        const int r = (rowbase) + wid * 16 + (lane & 15);                       \
        async16b(ls + (size_t)(bufb) * (bufsz) + (size_t)(rowbase) * 64 + wid * 1024, \
                 src + (size_t)((base0) + r) * 1024 + (kt) * 64 + ((lane >> 4) << 4)); \
    }

    int4v acc1[4][4], acc2[4][4];
    #pragma unroll
    for (int i = 0; i < 4; ++i)
        #pragma unroll
        for (int j = 0; j < 4; ++j) {
            acc1[i][j] = (int4v){0,0,0,0};
            acc2[i][j] = (int4v){0,0,0,0};
        }

    STGU(lAh, 0, 16384, 0,   Ah, m0, 0);
    STGU(lAh, 0, 16384, 128, Ah, m0, 0);
    STGU(lAl, 0, 16384, 0,   Al, m0, 0);
    STGU(lAl, 0, 16384, 128, Al, m0, 0);
    STGU(lBh, 0, 8192,  0,   Bh, n0, 0);
    STGU(lBl, 0, 8192,  0,   Bl, n0, 0);

    for (int kt = 0; kt < 16; ++kt) {
        const int bf = kt & 1, nb = bf ^ 1;
        asm volatile("s_waitcnt vmcnt(0)" ::: "memory");
        asm volatile("s_barrier" ::: "memory");
        // ---- phase 0: acc1 += Ah*Bh ----
        int4v ah[4], bh4[4];
        #pragma unroll
        for (int mi = 0; mi < 4; ++mi)
            ah[mi] = *(const int4v*)(lAh + (size_t)bf * 16384 +
                      (wr * 4 + mi) * 1024 + fro);
        #pragma unroll
        for (int nj = 0; nj < 4; ++nj)
            bh4[nj] = *(const int4v*)(lBh + (size_t)bf * 8192 +
                       (wc * 4 + nj) * 1024 + fro);
        if (kt < 15) {
            STGU(lAh, nb, 16384, 0,   Ah, m0, kt + 1);
            STGU(lAh, nb, 16384, 128, Ah, m0, kt + 1);
        }
        asm volatile("s_barrier" ::: "memory");
        __builtin_amdgcn_s_setprio(1);
        #pragma unroll
        for (int mi = 0; mi < 4; ++mi)
            #pragma unroll
            for (int nj = 0; nj < 4; ++nj)
                acc1[mi][nj] = __builtin_amdgcn_mfma_i32_16x16x64_i8(
                    ah[mi], bh4[nj], acc1[mi][nj], 0, 0, 0);
        __builtin_amdgcn_s_setprio(0);
        asm volatile("s_barrier" ::: "memory");
        // ---- phase 1: acc2 += Ah*Bl ----
        int4v bl4[4];
        #pragma unroll
        for (int nj = 0; nj < 4; ++nj)
            bl4[nj] = *(const int4v*)(lBl + (size_t)bf * 8192 +
                       (wc * 4 + nj) * 1024 + fro);
        if (kt < 15) {
            STGU(lAl, nb, 16384, 0,   Al, m0, kt + 1);
            STGU(lAl, nb, 16384, 128, Al, m0, kt + 1);
        }
        asm volatile("s_barrier" ::: "memory");
        __builtin_amdgcn_s_setprio(1);
        #pragma unroll
        for (int mi = 0; mi < 4; ++mi)
            #pragma unroll
            for (int nj = 0; nj < 4; ++nj)
                acc2[mi][nj] = __builtin_amdgcn_mfma_i32_16x16x64_i8(
                    ah[mi], bl4[nj], acc2[mi][nj], 0, 0, 0);
        __builtin_amdgcn_s_setprio(0);
        asm volatile("s_barrier" ::: "memory");
        // ---- phase 2: acc2 += Al*Bh ----
        int4v al[4];
        #pragma unroll
        for (int mi = 0; mi < 4; ++mi)
            al[mi] = *(const int4v*)(lAl + (size_t)bf * 16384 +
                      (wr * 4 + mi) * 1024 + fro);
        if (kt < 15) {
            STGU(lBh, nb, 8192, 0, Bh, n0, kt + 1);
            STGU(lBl, nb, 8192, 0, Bl, n0, kt + 1);
        }
        asm volatile("s_barrier" ::: "memory");
        __builtin_amdgcn_s_setprio(1);
        #pragma unroll
        for (int mi = 0; mi < 4; ++mi)
            #pragma unroll
            for (int nj = 0; nj < 4; ++nj)
                acc2[mi][nj] = __builtin_amdgcn_mfma_i32_16x16x64_i8(
                    al[mi], bh4[nj], acc2[mi][nj], 0, 0, 0);
        __builtin_amdgcn_s_setprio(0);
        asm volatile("s_barrier" ::: "memory");
    }

    #pragma unroll
    for (int nj = 0; nj < 4; ++nj) {
        const int n = n0 + wc * 64 + nj * 16 + r15;
        const float bs = bias[n];
        #pragma unroll
        for (int mi = 0; mi < 4; ++mi) {
            const int m = m0 + wr * 64 + mi * 16 + r4;
            const int b = m >> 11;
            const int l = m & 2047;
            s4v v;
            #pragma unroll
            for (int r = 0; r < 4; ++r)
                v[r] = (short)f2bf(fmaf(CS1, (float)acc1[mi][nj][r],
                                   fmaf(CS2, (float)acc2[mi][nj][r], bs)));
            *(s4v*)(outb + (((size_t)((b << 10) + n)) << 11) + l) = v;
        }
    }
    #undef STGU
}

// ---------------------------------------------------------------------------
// 256x256 phase-pipelined bf16 GEMM — unchanged
// ---------------------------------------------------------------------------
template<int EPI>
__global__ __launch_bounds__(512, 2) void gemm_bf16_256(
    const u16* __restrict__ A, const u16* __restrict__ B,
    const float* __restrict__ bias, const float* __restrict__ resid,
    float* __restrict__ outp)
{
    extern __shared__ u16 ldsx[];
    u16* lsA = ldsx;
    u16* lsB = ldsx + 32768;
    const int t = threadIdx.x;
    const int wid = t >> 6, lane = t & 63;
    const int wr = wid >> 2, wc = wid & 3;
    const int r15 = lane & 15, kg = lane >> 4, r4 = kg * 4;
    const int lin = blockIdx.y * gridDim.x + blockIdx.x;
    const int swz = (lin & 7) * 32 + (lin >> 3);
    const int n0 = (swz & 3) * 256, m0 = (swz >> 2) * 256;
    const int sb = wid * 2;
    const int sr = lane >> 3;
    const int ss = lane & 7;

    #define STG(bufb, ls, rb, src, base0, kt)                                   \
    {                                                                           \
        _Pragma("unroll")                                                       \
        for (int j = 0; j < 2; ++j) {                                           \
            const int r = (rb) + (sb + j) * 8 + sr;                             \
            async16(ls + (size_t)(bufb) * 16384 + (size_t)(rb) * 64 + (size_t)(sb + j) * 512, \
                    src + (size_t)((base0) + r) * 1024 + (kt) * 64 + ((ss ^ (r & 7)) << 3)); \
        }                                                                       \
    }

    f32x4 acc[8][4];
    #pragma unroll
    for (int i = 0; i < 8; ++i)
        #pragma unroll
        for (int j = 0; j < 4; ++j)
            acc[i][j] = (f32x4){0.f, 0.f, 0.f, 0.f};

    STG(0, lsB, 0,   B, n0, 0);
    STG(0, lsB, 128, B, n0, 0);
    STG(0, lsA, 0,   A, m0, 0);
    STG(0, lsA, 128, A, m0, 0);

    for (int kt = 0; kt < 16; ++kt) {
        const int bf = kt & 1, nb = bf ^ 1;
        asm volatile("s_waitcnt vmcnt(0)" ::: "memory");
        asm volatile("s_barrier" ::: "memory");
        short8 bfr[4][2];
        #pragma unroll
        for (int nj = 0; nj < 4; ++nj)
            #pragma unroll
            for (int ks = 0; ks < 2; ++ks) {
                const int row = wc * 64 + nj * 16 + r15;
                bfr[nj][ks] = *(const short8*)(lsB + (size_t)bf * 16384 +
                    (size_t)row * 64 + ((((ks << 2) + kg) ^ (row & 7)) << 3));
            }
        #pragma unroll
        for (int p = 0; p < 4; ++p) {
            short8 afr[2][2];
            #pragma unroll
            for (int mh = 0; mh < 2; ++mh)
                #pragma unroll
                for (int ks = 0; ks < 2; ++ks) {
                    const int row = wr * 128 + (p * 2 + mh) * 16 + r15;
                    afr[mh][ks] = *(const short8*)(lsA + (size_t)bf * 16384 +
                        (size_t)row * 64 + ((((ks << 2) + kg) ^ (row & 7)) << 3));
                }
            if (kt < 15) {
                if (p == 0)      { STG(nb, lsB, 0,   B, n0, kt + 1); }
                else if (p == 1) { STG(nb, lsB, 128, B, n0, kt + 1); }
                else if (p == 2) { STG(nb, lsA, 0,   A, m0, kt + 1); }
                else             { STG(nb, lsA, 128, A, m0, kt + 1); }
            }
            asm volatile("s_barrier" ::: "memory");
            __builtin_amdgcn_s_setprio(1);
            #pragma unroll
            for (int mh = 0; mh < 2; ++mh)
                #pragma unroll
                for (int nj = 0; nj < 4; ++nj)
                    #pragma unroll
                    for (int ks = 0; ks < 2; ++ks)
                        acc[p * 2 + mh][nj] = __builtin_amdgcn_mfma_f32_16x16x32_bf16(
                            afr[mh][ks], bfr[nj][ks], acc[p * 2 + mh][nj], 0, 0, 0);
            __builtin_amdgcn_s_setprio(0);
            asm volatile("s_barrier" ::: "memory");
        }
    }

    if (EPI == 2) {
        u16* outb = (u16*)outp;
        #pragma unroll
        for (int nj = 0; nj < 4; ++nj) {
            const int n = n0 + wc * 64 + nj * 16 + r15;
            const float bs = bias[n];
            #pragma unroll
            for (int mi = 0; mi < 8; ++mi) {
                const int m = m0 + wr * 128 + mi * 16 + r4;
                const int b = m >> 11;
                const int l = m & 2047;
                s4v v;
                #pragma unroll
                for (int r = 0; r < 4; ++r) v[r] = (short)f2bf(acc[mi][nj][r] + bs);
                *(s4v*)(outb + (((size_t)((b << 10) + n)) << 11) + l) = v;
            }
        }
    } else {
        #pragma unroll
        for (int mi = 0; mi < 8; ++mi) {
            #pragma unroll
            for (int r = 0; r < 4; ++r) {
                const int m = m0 + wr * 128 + mi * 16 + r4 + r;
                const float* rrow = resid + ((size_t)m << 10);
                float* orow = outp + ((size_t)m << 10);
                #pragma unroll
                for (int nj = 0; nj < 4; ++nj) {
                    const int n = n0 + wc * 64 + nj * 16 + r15;
                    orow[n] = acc[mi][nj][r] + bias[n] + rrow[n];
                }
            }
        }
    }
    #undef STG
}

// ---------------------------------------------------------------------------
// Radix-8 Stockham FFT, N=2048, stages [8,8,8,4], 256 threads.
// ---------------------------------------------------------------------------
#define IDX(i) ((i) + ((i) >> 3))
#define FFT_BUF 2304

__device__ __forceinline__ float2 c_add(float2 a, float2 b){ return make_float2(a.x+b.x, a.y+b.y); }
__device__ __forceinline__ float2 c_sub(float2 a, float2 b){ return make_float2(a.x-b.x, a.y-b.y); }
__device__ __forceinline__ float2 cmul(float2 a, float2 b){
    return make_float2(fmaf(a.x, b.x, -a.y*b.y), fmaf(a.x, b.y, a.y*b.x));
}
template<bool INV>
__device__ __forceinline__ float2 rot90(float2 z) {
    return INV ? make_float2(-z.y, z.x) : make_float2(z.y, -z.x);
}

template<bool INV>
__device__ __forceinline__ void dft8(const float2* a, float2* y) {
    const float r = 0.70710678118654752f;
    float2 e0 = c_add(a[0], a[4]), e1 = c_sub(a[0], a[4]);
    float2 e2 = c_add(a[2], a[6]), e3 = rot90<INV>(c_sub(a[2], a[6]));
    float2 E0 = c_add(e0, e2), E2 = c_sub(e0, e2);
    float2 E1 = c_add(e1, e3), E3 = c_sub(e1, e3);
    float2 o0 = c_add(a[1], a[5]), o1 = c_sub(a[1], a[5]);
    float2 o2 = c_add(a[3], a[7]), o3 = rot90<INV>(c_sub(a[3], a[7]));
    float2 O0 = c_add(o0, o2), O2 = c_sub(o0, o2);
    float2 O1 = c_add(o1, o3), O3 = c_sub(o1, o3);
    float2 T1 = INV ? make_float2(r*(O1.x - O1.y), r*(O1.x + O1.y))
                    : make_float2(r*(O1.x + O1.y), r*(O1.y - O1.x));
    float2 T2 = rot90<INV>(O2);
    float2 T3 = INV ? make_float2(-r*(O3.x + O3.y), r*(O3.x - O3.y))
                    : make_float2(r*(O3.y - O3.x), -r*(O3.x + O3.y));
    y[0] = c_add(E0, O0); y[4] = c_sub(E0, O0);
    y[1] = c_add(E1, T1); y[5] = c_sub(E1, T1);
    y[2] = c_add(E2, T2); y[6] = c_sub(E2, T2);
    y[3] = c_add(E3, T3); y[7] = c_sub(E3, T3);
}

template<bool INV>
__device__ float2* fft2048_r8(float2* bufA, float2* bufB, const float2* twd, int tid)
{
    float2* src = bufA;
    float2* dst = bufB;
    #pragma unroll
    for (int st = 0; st < 3; ++st) {
        const int s = 1 << (3 * st);
        const int u = tid;
        const int sp = u & ~(s - 1);
        float2 a[8], y[8];
        #pragma unroll
        for (int t = 0; t < 8; ++t) a[t] = src[IDX(u + (t << 8))];
        dft8<INV>(a, y);
        float2 w1 = twd[sp];
        if (INV) w1.y = -w1.y;
        const int ob = u + 7 * sp;
        dst[IDX(ob)]     = y[0];
        dst[IDX(ob + s)] = cmul(y[1], w1);
        float2 w = w1;
        #pragma unroll
        for (int t = 2; t < 8; ++t) {
            w = cmul(w, w1);
            dst[IDX(ob + t * s)] = cmul(y[t], w);
        }
        __syncthreads();
        float2* tmp = src; src = dst; dst = tmp;
    }
    #pragma unroll
    for (int h = 0; h < 2; ++h) {
        const int u = tid + (h << 8);
        float2 a0 = src[IDX(u)],        a1 = src[IDX(u + 512)];
        float2 a2 = src[IDX(u + 1024)], a3 = src[IDX(u + 1536)];
        float2 b0 = c_add(a0, a2), b1 = c_sub(a0, a2);
        float2 b2 = c_add(a1, a3), b3 = rot90<INV>(c_sub(a1, a3));
        dst[IDX(u)]        = c_add(b0, b2);
        dst[IDX(u + 512)]  = c_add(b1, b3);
        dst[IDX(u + 1024)] = c_sub(b0, b2);
        dst[IDX(u + 1536)] = c_sub(b1, b3);
    }
    __syncthreads();
    return dst;
}

// ---------------------------------------------------------------------------
// F1: per (b,h,d-octet): FFT z=q+ik (bf16 inputs), accumulate S=Q*conj(K).
// ---------------------------------------------------------------------------
__global__ __launch_bounds__(256) void fft_corr_partial(
    const u16* __restrict__ qT, const u16* __restrict__ kT,
    float* __restrict__ part)
{
    __shared__ float2 bufA[FFT_BUF];
    __shared__ float2 bufB[FFT_BUF];
    __shared__ float2 twd[256];
    const int tid = threadIdx.x;
    const int blk = blockIdx.x;
    const int bh  = blk >> 3, g = blk & 7;
    {
        float s, c;
        sincosf((float)tid * 3.0679615757712823e-3f, &s, &c);
        twd[tid] = make_float2(c, -s);
    }
    float2 racc[4];
    #pragma unroll
    for (int ii = 0; ii < 4; ++ii) racc[ii] = make_float2(0.f, 0.f);
    float2 racc4 = make_float2(0.f, 0.f);

    const u16* qbase = qT + ((size_t)bh * DKK + g * 8) * LL;
    const u16* kbase = kT + ((size_t)bh * DKK + g * 8) * LL;
    for (int dd = 0; dd < 8; ++dd) {
        __syncthreads();
        const u16* qr = qbase + (size_t)dd * LL;
        const u16* kr = kbase + (size_t)dd * LL;
        short8 q8 = *(const short8*)(qr + tid * 8);
        short8 k8 = *(const short8*)(kr + tid * 8);
        #pragma unroll
        for (int j = 0; j < 8; ++j)
            bufA[IDX(tid * 8 + j)] = make_float2(bf2f((u16)q8[j]), bf2f((u16)k8[j]));
        __syncthreads();
        float2* res = fft2048_r8<false>(bufA, bufB, twd, tid);
        #pragma unroll
        for (int ii = 0; ii < 4; ++ii) {
            const int f = tid + (ii << 8);
            float2 zf = res[IDX(f)];
            float2 zc = res[IDX((2048 - f) & 2047)];
            float2 Q = make_float2(0.5f*(zf.x + zc.x), 0.5f*(zf.y - zc.y));
            float2 K = make_float2(0.5f*(zf.y + zc.y), -0.5f*(zf.x - zc.x));
            racc[ii].x += Q.x*K.x + Q.y*K.y;
            racc[ii].y += Q.y*K.x - Q.x*K.y;
        }
        if (tid == 0) {
            float2 zf = res[IDX(1024)];
            racc4.x += zf.x * zf.y;
        }
    }
    float* po = part + (size_t)blk * PART_STRIDE;
    #pragma unroll
    for (int ii = 0; ii < 4; ++ii) {
        const int f = tid + (ii << 8);
        po[2*f]     = racc[ii].x;
        po[2*f + 1] = racc[ii].y;
    }
    if (tid == 0) { po[2048] = racc4.x; po[2049] = racc4.y; }
}

// ---------------------------------------------------------------------------
// F2: per (b,h): sum 8 partials, Hermitian-extend, inverse FFT, top-7, softmax.
// ---------------------------------------------------------------------------
__global__ __launch_bounds__(256) void fft_inv_topk(
    const float* __restrict__ part, float* __restrict__ out1,
    float* __restrict__ topw, int* __restrict__ topi)
{
    __shared__ float2 bufA[FFT_BUF];
    __shared__ float2 bufB[FFT_BUF];
    __shared__ float2 twd[256];
    __shared__ float  mv[2048];
    __shared__ float  rv[256];
    __shared__ int    ri[256];
    __shared__ float  selv[TOPK];
    __shared__ int    seli[TOPK];
    const int tid = threadIdx.x;
    const int bh  = blockIdx.x;
    {
        float s, c;
        sincosf((float)tid * 3.0679615757712823e-3f, &s, &c);
        twd[tid] = make_float2(c, -s);
    }
    for (int f = tid; f < 1025; f += 256) {
        float sx = 0.f, sy = 0.f;
        for (int g2 = 0; g2 < 8; ++g2) {
            const float* po = part + (size_t)(bh * 8 + g2) * PART_STRIDE + 2*f;
            sx += po[0]; sy += po[1];
        }
        bufA[IDX(f)] = make_float2(sx, sy);
        if (f > 0 && f < 1024) bufA[IDX(2048 - f)] = make_float2(sx, -sy);
    }
    __syncthreads();
    float2* res = fft2048_r8<true>(bufA, bufB, twd, tid);
    const float scale = 1.0f / (2048.0f * 64.0f);
    #pragma unroll
    for (int j = 0; j < 8; ++j) {
        const int l = tid + (j << 8);
        mv[l] = res[IDX(l)].x * scale;
    }
    __syncthreads();
    for (int it = 0; it < TOPK; ++it) {
        float bvv = -3.0e38f; int bii = 0;
        #pragma unroll
        for (int c = 0; c < 8; ++c) {
            const int idx = tid * 8 + c;
            const float v = mv[idx];
            if (v > bvv) { bvv = v; bii = idx; }
        }
        rv[tid] = bvv; ri[tid] = bii;
        __syncthreads();
        for (int off = 128; off > 0; off >>= 1) {
            if (tid < off) {
                const float v2 = rv[tid + off]; const int i2 = ri[tid + off];
                if (v2 > rv[tid] || (v2 == rv[tid] && i2 < ri[tid])) {
                    rv[tid] = v2; ri[tid] = i2;
                }
            }
            __syncthreads();
        }
        if (tid == 0) { selv[it] = rv[0]; seli[it] = ri[0]; mv[ri[0]] = -3.0e38f; }
        __syncthreads();
    }
    if (tid == 0) {
        const float mx = selv[0];
        float e[TOPK]; float ssum = 0.f;
        #pragma unroll
        for (int i = 0; i < TOPK; ++i) { e[i] = expf(selv[i] - mx); ssum += e[i]; }
        const float inv = 1.0f / ssum;
        #pragma unroll
        for (int i = 0; i < TOPK; ++i) {
            const float w = e[i] * inv;
            out1[bh * TOPK + i] = w;
            topw[bh * TOPK + i] = w;
            topi[bh * TOPK + i] = seli[i];
        }
    }
}

// ---------------------------------------------------------------------------
// Fused gather + transpose (dynamic LDS 131072 B)
// ---------------------------------------------------------------------------
__global__ __launch_bounds__(256) void gather_tr(
    const u16* __restrict__ vbf, const float* __restrict__ topw,
    const int* __restrict__ topi, u16* __restrict__ aggrow)
{
    extern __shared__ u16 vstage[];      // [32][2048]
    __shared__ float wv[TOPK];
    __shared__ int   wi[TOPK];
    const int blk  = blockIdx.x;         // bh*2 + half
    const int bh   = blk >> 1, half = blk & 1;
    const int b    = bh >> 4, h = bh & 15;
    const int tid  = threadIdx.x;
    if (tid < TOPK) {
        wv[tid] = topw[bh * TOPK + tid];
        wi[tid] = topi[bh * TOPK + tid];
    }
    const u16* vsrc = vbf + ((size_t)bh * DKK + half * 32) * LL;
    short8* vs8 = (short8*)vstage;
    #pragma unroll
    for (int k = 0; k < 32; ++k)
        vs8[tid + k * 256] = *(const short8*)(vsrc + (size_t)(tid + k * 256) * 8);
    __syncthreads();
    const int doff = h * 64 + half * 32;
    for (int c = 0; c < 8; ++c) {
        const int l = c * 256 + tid;
        u16* orow = aggrow + ((size_t)((b << 11) + l) << 10) + doff;
        short8 o[4];
        #pragma unroll
        for (int d = 0; d < 32; ++d) {
            float s = 0.f;
            #pragma unroll
            for (int i = 0; i < TOPK; ++i)
                s = fmaf(wv[i], bf2f(vstage[d * 2048 + ((l + wi[i]) & 2047)]), s);
            o[d >> 3][d & 7] = (short)f2bf(s);
        }
        #pragma unroll
        for (int q = 0; q < 4; ++q)
            *(short8*)(orow + q * 8) = o[q];
    }
}

// ---------------------------------------------------------------------------
extern "C" void kernel_launch(void* const* d_in, const int* in_sizes, int n_in,
                              void* d_out, int out_size, void* d_ws, size_t ws_size,
                              hipStream_t stream)
{
    const float* query = (const float*)d_in[0];
    const float* key   = (const float*)d_in[1];
    const float* value = (const float*)d_in[2];
    const float* Wq    = (const float*)d_in[3];
    const float* bq    = (const float*)d_in[4];
    const float* Wk    = (const float*)d_in[5];
    const float* bk    = (const float*)d_in[6];
    const float* Wv    = (const float*)d_in[7];
    const float* bv    = (const float*)d_in[8];
    const float* Wo    = (const float*)d_in[9];
    const float* bo    = (const float*)d_in[10];
    float* out = (float*)d_out;
    char*  ws  = (char*)d_ws;

    char* qxh = (char*)(ws + QXH_B);
    char* qxl = (char*)(ws + QXL_B);
    char* kxh = (char*)(ws + KXH_B);
    char* kxl = (char*)(ws + KXL_B);
    u16*  vxh = (u16*)(ws + VXH_B);
    char* qwh = (char*)(ws + QWH_B);
    char* qwl = (char*)(ws + QWL_B);
    char* kwh = (char*)(ws + KWH_B);
    char* kwl = (char*)(ws + KWL_B);
    u16*  vwh = (u16*)(ws + VWH_B);
    u16*  owh = (u16*)(ws + OWH_B);
    u16*  qTb = (u16*)(ws + QTB_B);
    u16*  kTb = (u16*)(ws + KTB_B);
    u16*  vbf = (u16*)(ws + VBF_B);
    float* part = (float*)(ws + PART_B);
    float* topw = (float*)(ws + TOPW_B);
    int*   topi = (int*)(ws + TOPI_B);
    u16*  aggrow = (u16*)(ws + QTB_B);   // reuse qTb after F1

    dim3 g2(DD / 256, (BB * LL) / 256);    // (4, 64)   for 256^2 bf16 GEMMs
    dim3 g4(DD / 128, (BB * LL) / 128);    // (8, 128)  = 1024 blocks merged i8

    // all conversions, one launch
    k_conv_all<<<26624, 256, 0, stream>>>(query, key, value, Wq, Wk, Wv, Wo,
                                          qxh, qxl, kxh, kxl, vxh,
                                          qwh, qwl, kwh, kwl, vwh, owh);
    // projections: merged Q+K i8 GEMM, then V bf16 GEMM
    gemm_i8_qk<<<g4, 512, 98304, stream>>>(qxh, qxl, qwh, qwl, bq, qTb,
                                           kxh, kxl, kwh, kwl, bk, kTb);
    gemm_bf16_256<2><<<g2, 512, 131072, stream>>>(vxh, vwh, bv, nullptr, (float*)vbf);
    // autocorrelation
    fft_corr_partial<<<BB * HH * 8, 256, 0, stream>>>(qTb, kTb, part);
    fft_inv_topk<<<BB * HH, 256, 0, stream>>>(part, out + 16777216, topw, topi);
    gather_tr<<<BB * HH * 2, 256, 131072, stream>>>(vbf, topw, topi, aggrow);
    // output projection + residual
    gemm_bf16_256<1><<<g2, 512, 131072, stream>>>(aggrow, owh, bo, query, out);
}

// Round 17
// 354.454 us; speedup vs baseline: 1.0609x; 1.0609x over previous
//
#include <hip/hip_runtime.h>
#include <hip/hip_bf16.h>
#include <math.h>

#define BB   8
#define LL   2048
#define DD   1024
#define HH   16
#define DKK  64
#define TOPK 7

typedef unsigned short u16;
typedef short short8 __attribute__((ext_vector_type(8)));
typedef short s4v    __attribute__((ext_vector_type(4)));
typedef float f32x4  __attribute__((ext_vector_type(4)));
typedef int   int4v  __attribute__((ext_vector_type(4)));
typedef unsigned int uint2v __attribute__((ext_vector_type(2)));

// ---- workspace layout (BYTE offsets), high-water = 209,715,200 B ----
#define QXH_B   0ull
#define QXL_B   16777216ull
#define KXH_B   33554432ull
#define KXL_B   50331648ull
#define VXH_B   67108864ull
#define QWH_B   100663296ull
#define QWL_B   101711872ull
#define KWH_B   102760448ull
#define KWL_B   103809024ull
#define VWH_B   104857600ull
#define OWH_B   106954752ull
#define QTB_B   109051904ull
#define KTB_B   142606336ull
#define VBF_B   176160768ull
#define PART_B  0ull
#define PART_STRIDE 2064
#define TOPW_B  16777216ull
#define TOPI_B  16780800ull

#define SX_INV  5461.3333f
#define SW_INV  174762.67f
#define CS1     6.8664551e-5f
#define CS2     2.6822090e-7f

// ---------------------------------------------------------------------------
// helpers
// ---------------------------------------------------------------------------
__device__ __forceinline__ u16 f2bf(float f) {
    unsigned u = __float_as_uint(f);
    unsigned r = u + 0x7FFFu + ((u >> 16) & 1u);
    return (u16)(r >> 16);
}
__device__ __forceinline__ float bf2f(u16 h) {
    return __uint_as_float((unsigned)h << 16);
}

// 8 elems/thread: 2x float4 load, hi/lo each packed into one 8B store
__device__ __forceinline__ void split8_i8(const float* __restrict__ x,
                                          char* __restrict__ hi,
                                          char* __restrict__ lo,
                                          float inv_s, size_t i) {
    const float4* xp = (const float4*)(x + i * 8);
    float4 t0 = xp[0], t1 = xp[1];
    float f[8] = {t0.x, t0.y, t0.z, t0.w, t1.x, t1.y, t1.z, t1.w};
    uint2v hp = (uint2v){0u, 0u}, lp = (uint2v){0u, 0u};
    #pragma unroll
    for (int j = 0; j < 8; ++j) {
        int q = __float2int_rn(f[j] * inv_s);
        q = min(max(q, -32639), 32639);
        int xl = ((q + 128) & 255) - 128;
        int xh = (q - xl) >> 8;
        hp[j >> 2] |= ((unsigned)(xh & 255)) << (8 * (j & 3));
        lp[j >> 2] |= ((unsigned)(xl & 255)) << (8 * (j & 3));
    }
    *(uint2v*)(hi + i * 8) = hp;
    *(uint2v*)(lo + i * 8) = lp;
}

// 8 elems/thread: 2x float4 load -> one short8 bf16 store (16B)
__device__ __forceinline__ void cvt8_bf(const float* __restrict__ x,
                                        u16* __restrict__ o, size_t i) {
    const float4* xp = (const float4*)(x + i * 8);
    float4 t0 = xp[0], t1 = xp[1];
    float f[8] = {t0.x, t0.y, t0.z, t0.w, t1.x, t1.y, t1.z, t1.w};
    short8 h;
    #pragma unroll
    for (int j = 0; j < 8; ++j) h[j] = (short)f2bf(f[j]);
    *(short8*)(o + i * 8) = h;
}

// ---------------------------------------------------------------------------
// ALL conversions, one launch, 8 elems/thread.
// ---------------------------------------------------------------------------
__global__ __launch_bounds__(256) void k_conv_all(
    const float* __restrict__ q, const float* __restrict__ k,
    const float* __restrict__ v,
    const float* __restrict__ Wq, const float* __restrict__ Wk,
    const float* __restrict__ Wv, const float* __restrict__ Wo,
    char* __restrict__ qh, char* __restrict__ ql,
    char* __restrict__ kh, char* __restrict__ kl, u16* __restrict__ vx,
    char* __restrict__ qwh, char* __restrict__ qwl,
    char* __restrict__ kwh, char* __restrict__ kwl,
    u16* __restrict__ vwh, u16* __restrict__ owh)
{
    const int b = blockIdx.x;
    const int t = threadIdx.x;
    if (b < 8192) {
        split8_i8(q, qh, ql, SX_INV, (size_t)b * 256 + t);
    } else if (b < 16384) {
        split8_i8(k, kh, kl, SX_INV, (size_t)(b - 8192) * 256 + t);
    } else if (b < 24576) {
        cvt8_bf(v, vx, (size_t)(b - 16384) * 256 + t);
    } else if (b < 25088) {
        split8_i8(Wq, qwh, qwl, SW_INV, (size_t)(b - 24576) * 256 + t);
    } else if (b < 25600) {
        split8_i8(Wk, kwh, kwl, SW_INV, (size_t)(b - 25088) * 256 + t);
    } else if (b < 26112) {
        cvt8_bf(Wv, vwh, (size_t)(b - 25600) * 256 + t);
    } else {
        cvt8_bf(Wo, owh, (size_t)(b - 26112) * 256 + t);
    }
}

// ---------------------------------------------------------------------------
// async global->LDS (16B, wave-uniform LDS base + lane*16)
// ---------------------------------------------------------------------------
__device__ __forceinline__ void async16(u16* l, const u16* g) {
    __builtin_amdgcn_global_load_lds(
        (const __attribute__((address_space(1))) void*)g,
        (__attribute__((address_space(3))) void*)l, 16, 0, 0);
}
__device__ __forceinline__ void async16b(char* l, const char* g) {
    __builtin_amdgcn_global_load_lds(
        (const __attribute__((address_space(1))) void*)g,
        (__attribute__((address_space(3))) void*)l, 16, 0, 0);
}

// ---------------------------------------------------------------------------
// MERGED 256x128 phase-pipelined i8-split GEMM (Round-15 structure, fixed
// bank swizzle): slot XOR index = (row>>1)&3 (not row&3). 64B rows alias
// banks on row&1 only, so this gives 2-way max (free, m136) while keeping
// 64B-contiguous global staging (4 lanes per row cover all 4 chunks).
// ---------------------------------------------------------------------------
__global__ __launch_bounds__(512, 2) void gemm_i8_qk(
    const char* __restrict__ qAh, const char* __restrict__ qAl,
    const char* __restrict__ qBh, const char* __restrict__ qBl,
    const float* __restrict__ qbias, u16* __restrict__ qout,
    const char* __restrict__ kAh, const char* __restrict__ kAl,
    const char* __restrict__ kBh, const char* __restrict__ kBl,
    const float* __restrict__ kbias, u16* __restrict__ kout)
{
    extern __shared__ char ldsc[];
    char* lAh = ldsc;
    char* lAl = ldsc + 32768;
    char* lBh = ldsc + 65536;
    char* lBl = ldsc + 81920;
    const int t = threadIdx.x;
    const int wid = t >> 6, lane = t & 63;
    const int wr = wid >> 1, wc = wid & 1;
    const int r15 = lane & 15, kg = lane >> 4, r4 = kg * 4;
    const int lin = blockIdx.y * gridDim.x + blockIdx.x;   // [0,1024)
    const int set = lin >> 9;                              // 0=Q, 1=K
    const int l2  = lin & 511;
    const int swz = (l2 & 7) * 64 + (l2 >> 3);             // bijective per set
    const int n0 = (swz & 7) * 128, m0 = (swz >> 3) * 256;
    const char* Ah = set ? kAh : qAh;
    const char* Al = set ? kAl : qAl;
    const char* Bh = set ? kBh : qBh;
    const char* Bl = set ? kBl : qBl;
    const float* bias = set ? kbias : qbias;
    u16* outb = set ? kout : qout;
    // fragment-read byte offset: slot = kg ^ ((r15>>1)&3), 2-way banks (free)
    const int swzrd = ((kg ^ ((r15 >> 1) & 3)) << 4);

    // stage one 8KB unit: 4 lanes per row cover all 4 chunks (64B contiguous)
    #define STGU(ls, bufb, bufsz, rowbase, src, base0, kt)                      \
    {                                                                           \
        const int r = (rowbase) + wid * 16 + (lane >> 2);                       \
        async16b(ls + (size_t)(bufb) * (bufsz) + (size_t)(rowbase) * 64 + wid * 1024, \
                 src + (size_t)((base0) + r) * 1024 + (kt) * 64 + (((lane & 3) ^ ((r >> 1) & 3)) << 4)); \
    }

    int4v acc1[4][4], acc2[4][4];
    #pragma unroll
    for (int i = 0; i < 4; ++i)
        #pragma unroll
        for (int j = 0; j < 4; ++j) {
            acc1[i][j] = (int4v){0,0,0,0};
            acc2[i][j] = (int4v){0,0,0,0};
        }

    STGU(lAh, 0, 16384, 0,   Ah, m0, 0);
    STGU(lAh, 0, 16384, 128, Ah, m0, 0);
    STGU(lAl, 0, 16384, 0,   Al, m0, 0);
    STGU(lAl, 0, 16384, 128, Al, m0, 0);
    STGU(lBh, 0, 8192,  0,   Bh, n0, 0);
    STGU(lBl, 0, 8192,  0,   Bl, n0, 0);

    for (int kt = 0; kt < 16; ++kt) {
        const int bf = kt & 1, nb = bf ^ 1;
        asm volatile("s_waitcnt vmcnt(0)" ::: "memory");
        asm volatile("s_barrier" ::: "memory");
        // ---- phase 0: acc1 += Ah*Bh ----
        int4v ah[4], bh4[4];
        #pragma unroll
        for (int mi = 0; mi < 4; ++mi) {
            const int row = wr * 64 + mi * 16 + r15;
            ah[mi] = *(const int4v*)(lAh + (size_t)bf * 16384 +
                      (size_t)row * 64 + swzrd);
        }
        #pragma unroll
        for (int nj = 0; nj < 4; ++nj) {
            const int row = wc * 64 + nj * 16 + r15;
            bh4[nj] = *(const int4v*)(lBh + (size_t)bf * 8192 +
                       (size_t)row * 64 + swzrd);
        }
        if (kt < 15) {
            STGU(lAh, nb, 16384, 0,   Ah, m0, kt + 1);
            STGU(lAh, nb, 16384, 128, Ah, m0, kt + 1);
        }
        asm volatile("s_barrier" ::: "memory");
        __builtin_amdgcn_s_setprio(1);
        #pragma unroll
        for (int mi = 0; mi < 4; ++mi)
            #pragma unroll
            for (int nj = 0; nj < 4; ++nj)
                acc1[mi][nj] = __builtin_amdgcn_mfma_i32_16x16x64_i8(
                    ah[mi], bh4[nj], acc1[mi][nj], 0, 0, 0);
        __builtin_amdgcn_s_setprio(0);
        asm volatile("s_barrier" ::: "memory");
        // ---- phase 1: acc2 += Ah*Bl ----
        int4v bl4[4];
        #pragma unroll
        for (int nj = 0; nj < 4; ++nj) {
            const int row = wc * 64 + nj * 16 + r15;
            bl4[nj] = *(const int4v*)(lBl + (size_t)bf * 8192 +
                       (size_t)row * 64 + swzrd);
        }
        if (kt < 15) {
            STGU(lAl, nb, 16384, 0,   Al, m0, kt + 1);
            STGU(lAl, nb, 16384, 128, Al, m0, kt + 1);
        }
        asm volatile("s_barrier" ::: "memory");
        __builtin_amdgcn_s_setprio(1);
        #pragma unroll
        for (int mi = 0; mi < 4; ++mi)
            #pragma unroll
            for (int nj = 0; nj < 4; ++nj)
                acc2[mi][nj] = __builtin_amdgcn_mfma_i32_16x16x64_i8(
                    ah[mi], bl4[nj], acc2[mi][nj], 0, 0, 0);
        __builtin_amdgcn_s_setprio(0);
        asm volatile("s_barrier" ::: "memory");
        // ---- phase 2: acc2 += Al*Bh ----
        int4v al[4];
        #pragma unroll
        for (int mi = 0; mi < 4; ++mi) {
            const int row = wr * 64 + mi * 16 + r15;
            al[mi] = *(const int4v*)(lAl + (size_t)bf * 16384 +
                      (size_t)row * 64 + swzrd);
        }
        if (kt < 15) {
            STGU(lBh, nb, 8192, 0, Bh, n0, kt + 1);
            STGU(lBl, nb, 8192, 0, Bl, n0, kt + 1);
        }
        asm volatile("s_barrier" ::: "memory");
        __builtin_amdgcn_s_setprio(1);
        #pragma unroll
        for (int mi = 0; mi < 4; ++mi)
            #pragma unroll
            for (int nj = 0; nj < 4; ++nj)
                acc2[mi][nj] = __builtin_amdgcn_mfma_i32_16x16x64_i8(
                    al[mi], bh4[nj], acc2[mi][nj], 0, 0, 0);
        __builtin_amdgcn_s_setprio(0);
        asm volatile("s_barrier" ::: "memory");
    }

    #pragma unroll
    for (int nj = 0; nj < 4; ++nj) {
        const int n = n0 + wc * 64 + nj * 16 + r15;
        const float bs = bias[n];
        #pragma unroll
        for (int mi = 0; mi < 4; ++mi) {
            const int m = m0 + wr * 64 + mi * 16 + r4;
            const int b = m >> 11;
            const int l = m & 2047;
            s4v v;
            #pragma unroll
            for (int r = 0; r < 4; ++r)
                v[r] = (short)f2bf(fmaf(CS1, (float)acc1[mi][nj][r],
                                   fmaf(CS2, (float)acc2[mi][nj][r], bs)));
            *(s4v*)(outb + (((size_t)((b << 10) + n)) << 11) + l) = v;
        }
    }
    #undef STGU
}

// ---------------------------------------------------------------------------
// 256x256 phase-pipelined bf16 GEMM — unchanged
// ---------------------------------------------------------------------------
template<int EPI>
__global__ __launch_bounds__(512, 2) void gemm_bf16_256(
    const u16* __restrict__ A, const u16* __restrict__ B,
    const float* __restrict__ bias, const float* __restrict__ resid,
    float* __restrict__ outp)
{
    extern __shared__ u16 ldsx[];
    u16* lsA = ldsx;
    u16* lsB = ldsx + 32768;
    const int t = threadIdx.x;
    const int wid = t >> 6, lane = t & 63;
    const int wr = wid >> 2, wc = wid & 3;
    const int r15 = lane & 15, kg = lane >> 4, r4 = kg * 4;
    const int lin = blockIdx.y * gridDim.x + blockIdx.x;
    const int swz = (lin & 7) * 32 + (lin >> 3);
    const int n0 = (swz & 3) * 256, m0 = (swz >> 2) * 256;
    const int sb = wid * 2;
    const int sr = lane >> 3;
    const int ss = lane & 7;

    #define STG(bufb, ls, rb, src, base0, kt)                                   \
    {                                                                           \
        _Pragma("unroll")                                                       \
        for (int j = 0; j < 2; ++j) {                                           \
            const int r = (rb) + (sb + j) * 8 + sr;                             \
            async16(ls + (size_t)(bufb) * 16384 + (size_t)(rb) * 64 + (size_t)(sb + j) * 512, \
                    src + (size_t)((base0) + r) * 1024 + (kt) * 64 + ((ss ^ (r & 7)) << 3)); \
        }                                                                       \
    }

    f32x4 acc[8][4];
    #pragma unroll
    for (int i = 0; i < 8; ++i)
        #pragma unroll
        for (int j = 0; j < 4; ++j)
            acc[i][j] = (f32x4){0.f, 0.f, 0.f, 0.f};

    STG(0, lsB, 0,   B, n0, 0);
    STG(0, lsB, 128, B, n0, 0);
    STG(0, lsA, 0,   A, m0, 0);
    STG(0, lsA, 128, A, m0, 0);

    for (int kt = 0; kt < 16; ++kt) {
        const int bf = kt & 1, nb = bf ^ 1;
        asm volatile("s_waitcnt vmcnt(0)" ::: "memory");
        asm volatile("s_barrier" ::: "memory");
        short8 bfr[4][2];
        #pragma unroll
        for (int nj = 0; nj < 4; ++nj)
            #pragma unroll
            for (int ks = 0; ks < 2; ++ks) {
                const int row = wc * 64 + nj * 16 + r15;
                bfr[nj][ks] = *(const short8*)(lsB + (size_t)bf * 16384 +
                    (size_t)row * 64 + ((((ks << 2) + kg) ^ (row & 7)) << 3));
            }
        #pragma unroll
        for (int p = 0; p < 4; ++p) {
            short8 afr[2][2];
            #pragma unroll
            for (int mh = 0; mh < 2; ++mh)
                #pragma unroll
                for (int ks = 0; ks < 2; ++ks) {
                    const int row = wr * 128 + (p * 2 + mh) * 16 + r15;
                    afr[mh][ks] = *(const short8*)(lsA + (size_t)bf * 16384 +
                        (size_t)row * 64 + ((((ks << 2) + kg) ^ (row & 7)) << 3));
                }
            if (kt < 15) {
                if (p == 0)      { STG(nb, lsB, 0,   B, n0, kt + 1); }
                else if (p == 1) { STG(nb, lsB, 128, B, n0, kt + 1); }
                else if (p == 2) { STG(nb, lsA, 0,   A, m0, kt + 1); }
                else             { STG(nb, lsA, 128, A, m0, kt + 1); }
            }
            asm volatile("s_barrier" ::: "memory");
            __builtin_amdgcn_s_setprio(1);
            #pragma unroll
            for (int mh = 0; mh < 2; ++mh)
                #pragma unroll
                for (int nj = 0; nj < 4; ++nj)
                    #pragma unroll
                    for (int ks = 0; ks < 2; ++ks)
                        acc[p * 2 + mh][nj] = __builtin_amdgcn_mfma_f32_16x16x32_bf16(
                            afr[mh][ks], bfr[nj][ks], acc[p * 2 + mh][nj], 0, 0, 0);
            __builtin_amdgcn_s_setprio(0);
            asm volatile("s_barrier" ::: "memory");
        }
    }

    if (EPI == 2) {
        u16* outb = (u16*)outp;
        #pragma unroll
        for (int nj = 0; nj < 4; ++nj) {
            const int n = n0 + wc * 64 + nj * 16 + r15;
            const float bs = bias[n];
            #pragma unroll
            for (int mi = 0; mi < 8; ++mi) {
                const int m = m0 + wr * 128 + mi * 16 + r4;
                const int b = m >> 11;
                const int l = m & 2047;
                s4v v;
                #pragma unroll
                for (int r = 0; r < 4; ++r) v[r] = (short)f2bf(acc[mi][nj][r] + bs);
                *(s4v*)(outb + (((size_t)((b << 10) + n)) << 11) + l) = v;
            }
        }
    } else {
        #pragma unroll
        for (int mi = 0; mi < 8; ++mi) {
            #pragma unroll
            for (int r = 0; r < 4; ++r) {
                const int m = m0 + wr * 128 + mi * 16 + r4 + r;
                const float* rrow = resid + ((size_t)m << 10);
                float* orow = outp + ((size_t)m << 10);
                #pragma unroll
                for (int nj = 0; nj < 4; ++nj) {
                    const int n = n0 + wc * 64 + nj * 16 + r15;
                    orow[n] = acc[mi][nj][r] + bias[n] + rrow[n];
                }
            }
        }
    }
    #undef STG
}

// ---------------------------------------------------------------------------
// Radix-8 Stockham FFT, N=2048, stages [8,8,8,4], 256 threads.
// ---------------------------------------------------------------------------
#define IDX(i) ((i) + ((i) >> 3))
#define FFT_BUF 2304

__device__ __forceinline__ float2 c_add(float2 a, float2 b){ return make_float2(a.x+b.x, a.y+b.y); }
__device__ __forceinline__ float2 c_sub(float2 a, float2 b){ return make_float2(a.x-b.x, a.y-b.y); }
__device__ __forceinline__ float2 cmul(float2 a, float2 b){
    return make_float2(fmaf(a.x, b.x, -a.y*b.y), fmaf(a.x, b.y, a.y*b.x));
}
template<bool INV>
__device__ __forceinline__ float2 rot90(float2 z) {
    return INV ? make_float2(-z.y, z.x) : make_float2(z.y, -z.x);
}

template<bool INV>
__device__ __forceinline__ void dft8(const float2* a, float2* y) {
    const float r = 0.70710678118654752f;
    float2 e0 = c_add(a[0], a[4]), e1 = c_sub(a[0], a[4]);
    float2 e2 = c_add(a[2], a[6]), e3 = rot90<INV>(c_sub(a[2], a[6]));
    float2 E0 = c_add(e0, e2), E2 = c_sub(e0, e2);
    float2 E1 = c_add(e1, e3), E3 = c_sub(e1, e3);
    float2 o0 = c_add(a[1], a[5]), o1 = c_sub(a[1], a[5]);
    float2 o2 = c_add(a[3], a[7]), o3 = rot90<INV>(c_sub(a[3], a[7]));
    float2 O0 = c_add(o0, o2), O2 = c_sub(o0, o2);
    float2 O1 = c_add(o1, o3), O3 = c_sub(o1, o3);
    float2 T1 = INV ? make_float2(r*(O1.x - O1.y), r*(O1.x + O1.y))
                    : make_float2(r*(O1.x + O1.y), r*(O1.y - O1.x));
    float2 T2 = rot90<INV>(O2);
    float2 T3 = INV ? make_float2(-r*(O3.x + O3.y), r*(O3.x - O3.y))
                    : make_float2(r*(O3.y - O3.x), -r*(O3.x + O3.y));
    y[0] = c_add(E0, O0); y[4] = c_sub(E0, O0);
    y[1] = c_add(E1, T1); y[5] = c_sub(E1, T1);
    y[2] = c_add(E2, T2); y[6] = c_sub(E2, T2);
    y[3] = c_add(E3, T3); y[7] = c_sub(E3, T3);
}

template<bool INV>
__device__ float2* fft2048_r8(float2* bufA, float2* bufB, const float2* twd, int tid)
{
    float2* src = bufA;
    float2* dst = bufB;
    #pragma unroll
    for (int st = 0; st < 3; ++st) {
        const int s = 1 << (3 * st);
        const int u = tid;
        const int sp = u & ~(s - 1);
        float2 a[8], y[8];
        #pragma unroll
        for (int t = 0; t < 8; ++t) a[t] = src[IDX(u + (t << 8))];
        dft8<INV>(a, y);
        float2 w1 = twd[sp];
        if (INV) w1.y = -w1.y;
        const int ob = u + 7 * sp;
        dst[IDX(ob)]     = y[0];
        dst[IDX(ob + s)] = cmul(y[1], w1);
        float2 w = w1;
        #pragma unroll
        for (int t = 2; t < 8; ++t) {
            w = cmul(w, w1);
            dst[IDX(ob + t * s)] = cmul(y[t], w);
        }
        __syncthreads();
        float2* tmp = src; src = dst; dst = tmp;
    }
    #pragma unroll
    for (int h = 0; h < 2; ++h) {
        const int u = tid + (h << 8);
        float2 a0 = src[IDX(u)],        a1 = src[IDX(u + 512)];
        float2 a2 = src[IDX(u + 1024)], a3 = src[IDX(u + 1536)];
        float2 b0 = c_add(a0, a2), b1 = c_sub(a0, a2);
        float2 b2 = c_add(a1, a3), b3 = rot90<INV>(c_sub(a1, a3));
        dst[IDX(u)]        = c_add(b0, b2);
        dst[IDX(u + 512)]  = c_add(b1, b3);
        dst[IDX(u + 1024)] = c_sub(b0, b2);
        dst[IDX(u + 1536)] = c_sub(b1, b3);
    }
    __syncthreads();
    return dst;
}

// ---------------------------------------------------------------------------
// F1: per (b,h,d-octet): FFT z=q+ik (bf16 inputs), accumulate S=Q*conj(K).
// ---------------------------------------------------------------------------
__global__ __launch_bounds__(256) void fft_corr_partial(
    const u16* __restrict__ qT, const u16* __restrict__ kT,
    float* __restrict__ part)
{
    __shared__ float2 bufA[FFT_BUF];
    __shared__ float2 bufB[FFT_BUF];
    __shared__ float2 twd[256];
    const int tid = threadIdx.x;
    const int blk = blockIdx.x;
    const int bh  = blk >> 3, g = blk & 7;
    {
        float s, c;
        sincosf((float)tid * 3.0679615757712823e-3f, &s, &c);
        twd[tid] = make_float2(c, -s);
    }
    float2 racc[4];
    #pragma unroll
    for (int ii = 0; ii < 4; ++ii) racc[ii] = make_float2(0.f, 0.f);
    float2 racc4 = make_float2(0.f, 0.f);

    const u16* qbase = qT + ((size_t)bh * DKK + g * 8) * LL;
    const u16* kbase = kT + ((size_t)bh * DKK + g * 8) * LL;
    for (int dd = 0; dd < 8; ++dd) {
        __syncthreads();
        const u16* qr = qbase + (size_t)dd * LL;
        const u16* kr = kbase + (size_t)dd * LL;
        short8 q8 = *(const short8*)(qr + tid * 8);
        short8 k8 = *(const short8*)(kr + tid * 8);
        #pragma unroll
        for (int j = 0; j < 8; ++j)
            bufA[IDX(tid * 8 + j)] = make_float2(bf2f((u16)q8[j]), bf2f((u16)k8[j]));
        __syncthreads();
        float2* res = fft2048_r8<false>(bufA, bufB, twd, tid);
        #pragma unroll
        for (int ii = 0; ii < 4; ++ii) {
            const int f = tid + (ii << 8);
            float2 zf = res[IDX(f)];
            float2 zc = res[IDX((2048 - f) & 2047)];
            float2 Q = make_float2(0.5f*(zf.x + zc.x), 0.5f*(zf.y - zc.y));
            float2 K = make_float2(0.5f*(zf.y + zc.y), -0.5f*(zf.x - zc.x));
            racc[ii].x += Q.x*K.x + Q.y*K.y;
            racc[ii].y += Q.y*K.x - Q.x*K.y;
        }
        if (tid == 0) {
            float2 zf = res[IDX(1024)];
            racc4.x += zf.x * zf.y;
        }
    }
    float* po = part + (size_t)blk * PART_STRIDE;
    #pragma unroll
    for (int ii = 0; ii < 4; ++ii) {
        const int f = tid + (ii << 8);
        po[2*f]     = racc[ii].x;
        po[2*f + 1] = racc[ii].y;
    }
    if (tid == 0) { po[2048] = racc4.x; po[2049] = racc4.y; }
}

// ---------------------------------------------------------------------------
// F2: per (b,h): sum 8 partials, Hermitian-extend, inverse FFT, top-7, softmax.
// ---------------------------------------------------------------------------
__global__ __launch_bounds__(256) void fft_inv_topk(
    const float* __restrict__ part, float* __restrict__ out1,
    float* __restrict__ topw, int* __restrict__ topi)
{
    __shared__ float2 bufA[FFT_BUF];
    __shared__ float2 bufB[FFT_BUF];
    __shared__ float2 twd[256];
    __shared__ float  mv[2048];
    __shared__ float  rv[256];
    __shared__ int    ri[256];
    __shared__ float  selv[TOPK];
    __shared__ int    seli[TOPK];
    const int tid = threadIdx.x;
    const int bh  = blockIdx.x;
    {
        float s, c;
        sincosf((float)tid * 3.0679615757712823e-3f, &s, &c);
        twd[tid] = make_float2(c, -s);
    }
    for (int f = tid; f < 1025; f += 256) {
        float sx = 0.f, sy = 0.f;
        for (int g2 = 0; g2 < 8; ++g2) {
            const float* po = part + (size_t)(bh * 8 + g2) * PART_STRIDE + 2*f;
            sx += po[0]; sy += po[1];
        }
        bufA[IDX(f)] = make_float2(sx, sy);
        if (f > 0 && f < 1024) bufA[IDX(2048 - f)] = make_float2(sx, -sy);
    }
    __syncthreads();
    float2* res = fft2048_r8<true>(bufA, bufB, twd, tid);
    const float scale = 1.0f / (2048.0f * 64.0f);
    #pragma unroll
    for (int j = 0; j < 8; ++j) {
        const int l = tid + (j << 8);
        mv[l] = res[IDX(l)].x * scale;
    }
    __syncthreads();
    for (int it = 0; it < TOPK; ++it) {
        float bvv = -3.0e38f; int bii = 0;
        #pragma unroll
        for (int c = 0; c < 8; ++c) {
            const int idx = tid * 8 + c;
            const float v = mv[idx];
            if (v > bvv) { bvv = v; bii = idx; }
        }
        rv[tid] = bvv; ri[tid] = bii;
        __syncthreads();
        for (int off = 128; off > 0; off >>= 1) {
            if (tid < off) {
                const float v2 = rv[tid + off]; const int i2 = ri[tid + off];
                if (v2 > rv[tid] || (v2 == rv[tid] && i2 < ri[tid])) {
                    rv[tid] = v2; ri[tid] = i2;
                }
            }
            __syncthreads();
        }
        if (tid == 0) { selv[it] = rv[0]; seli[it] = ri[0]; mv[ri[0]] = -3.0e38f; }
        __syncthreads();
    }
    if (tid == 0) {
        const float mx = selv[0];
        float e[TOPK]; float ssum = 0.f;
        #pragma unroll
        for (int i = 0; i < TOPK; ++i) { e[i] = expf(selv[i] - mx); ssum += e[i]; }
        const float inv = 1.0f / ssum;
        #pragma unroll
        for (int i = 0; i < TOPK; ++i) {
            const float w = e[i] * inv;
            out1[bh * TOPK + i] = w;
            topw[bh * TOPK + i] = w;
            topi[bh * TOPK + i] = seli[i];
        }
    }
}

// ---------------------------------------------------------------------------
// Fused gather + transpose (dynamic LDS 131072 B)
// ---------------------------------------------------------------------------
__global__ __launch_bounds__(256) void gather_tr(
    const u16* __restrict__ vbf, const float* __restrict__ topw,
    const int* __restrict__ topi, u16* __restrict__ aggrow)
{
    extern __shared__ u16 vstage[];      // [32][2048]
    __shared__ float wv[TOPK];
    __shared__ int   wi[TOPK];
    const int blk  = blockIdx.x;         // bh*2 + half
    const int bh   = blk >> 1, half = blk & 1;
    const int b    = bh >> 4, h = bh & 15;
    const int tid  = threadIdx.x;
    if (tid < TOPK) {
        wv[tid] = topw[bh * TOPK + tid];
        wi[tid] = topi[bh * TOPK + tid];
    }
    const u16* vsrc = vbf + ((size_t)bh * DKK + half * 32) * LL;
    short8* vs8 = (short8*)vstage;
    #pragma unroll
    for (int k = 0; k < 32; ++k)
        vs8[tid + k * 256] = *(const short8*)(vsrc + (size_t)(tid + k * 256) * 8);
    __syncthreads();
    const int doff = h * 64 + half * 32;
    for (int c = 0; c < 8; ++c) {
        const int l = c * 256 + tid;
        u16* orow = aggrow + ((size_t)((b << 11) + l) << 10) + doff;
        short8 o[4];
        #pragma unroll
        for (int d = 0; d < 32; ++d) {
            float s = 0.f;
            #pragma unroll
            for (int i = 0; i < TOPK; ++i)
                s = fmaf(wv[i], bf2f(vstage[d * 2048 + ((l + wi[i]) & 2047)]), s);
            o[d >> 3][d & 7] = (short)f2bf(s);
        }
        #pragma unroll
        for (int q = 0; q < 4; ++q)
            *(short8*)(orow + q * 8) = o[q];
    }
}

// ---------------------------------------------------------------------------
extern "C" void kernel_launch(void* const* d_in, const int* in_sizes, int n_in,
                              void* d_out, int out_size, void* d_ws, size_t ws_size,
                              hipStream_t stream)
{
    const float* query = (const float*)d_in[0];
    const float* key   = (const float*)d_in[1];
    const float* value = (const float*)d_in[2];
    const float* Wq    = (const float*)d_in[3];
    const float* bq    = (const float*)d_in[4];
    const float* Wk    = (const float*)d_in[5];
    const float* bk    = (const float*)d_in[6];
    const float* Wv    = (const float*)d_in[7];
    const float* bv    = (const float*)d_in[8];
    const float* Wo    = (const float*)d_in[9];
    const float* bo    = (const float*)d_in[10];
    float* out = (float*)d_out;
    char*  ws  = (char*)d_ws;

    char* qxh = (char*)(ws + QXH_B);
    char* qxl = (char*)(ws + QXL_B);
    char* kxh = (char*)(ws + KXH_B);
    char* kxl = (char*)(ws + KXL_B);
    u16*  vxh = (u16*)(ws + VXH_B);
    char* qwh = (char*)(ws + QWH_B);
    char* qwl = (char*)(ws + QWL_B);
    char* kwh = (char*)(ws + KWH_B);
    char* kwl = (char*)(ws + KWL_B);
    u16*  vwh = (u16*)(ws + VWH_B);
    u16*  owh = (u16*)(ws + OWH_B);
    u16*  qTb = (u16*)(ws + QTB_B);
    u16*  kTb = (u16*)(ws + KTB_B);
    u16*  vbf = (u16*)(ws + VBF_B);
    float* part = (float*)(ws + PART_B);
    float* topw = (float*)(ws + TOPW_B);
    int*   topi = (int*)(ws + TOPI_B);
    u16*  aggrow = (u16*)(ws + QTB_B);   // reuse qTb after F1

    dim3 g2(DD / 256, (BB * LL) / 256);    // (4, 64)   for 256^2 bf16 GEMMs
    dim3 g4(DD / 128, (BB * LL) / 128);    // (8, 128)  = 1024 blocks merged i8

    // all conversions, one launch
    k_conv_all<<<26624, 256, 0, stream>>>(query, key, value, Wq, Wk, Wv, Wo,
                                          qxh, qxl, kxh, kxl, vxh,
                                          qwh, qwl, kwh, kwl, vwh, owh);
    // projections: merged Q+K i8 GEMM, then V bf16 GEMM
    gemm_i8_qk<<<g4, 512, 98304, stream>>>(qxh, qxl, qwh, qwl, bq, qTb,
                                           kxh, kxl, kwh, kwl, bk, kTb);
    gemm_bf16_256<2><<<g2, 512, 131072, stream>>>(vxh, vwh, bv, nullptr, (float*)vbf);
    // autocorrelation
    fft_corr_partial<<<BB * HH * 8, 256, 0, stream>>>(qTb, kTb, part);
    fft_inv_topk<<<BB * HH, 256, 0, stream>>>(part, out + 16777216, topw, topi);
    gather_tr<<<BB * HH * 2, 256, 131072, stream>>>(vbf, topw, topi, aggrow);
    // output projection + residual
    gemm_bf16_256<1><<<g2, 512, 131072, stream>>>(aggrow, owh, bo, query, out);
}